// Round 4
// baseline (159.835 us; speedup 1.0000x reference)
//
#include <hip/hip_runtime.h>
#include <hip/hip_bf16.h>
#include <stdint.h>

#define NROWS 8192
#define DIM 512

typedef short bf16x8 __attribute__((ext_vector_type(8)));
typedef float f32x4 __attribute__((ext_vector_type(4)));

__device__ __forceinline__ unsigned short f2bf(float f) {
    union { float f; uint32_t u; } c; c.f = f;
    uint32_t u = c.u;
    return (unsigned short)((u + 0x7FFFu + ((u >> 16) & 1u)) >> 16);
}

// ---------------- Kernel 1: L2-normalize rows -> bf16; also zero pos/neg ----------------
__global__ __launch_bounds__(256) void knorm(const float* __restrict__ in,
                                             unsigned short* __restrict__ out,
                                             float* __restrict__ pos,
                                             float* __restrict__ neg) {
    const int row  = (blockIdx.x << 2) + (threadIdx.x >> 6);
    const int lane = threadIdx.x & 63;
    if (threadIdx.x < 4)      pos[(blockIdx.x << 2) + threadIdx.x] = 0.0f;
    else if (threadIdx.x < 8) neg[(blockIdx.x << 2) + threadIdx.x - 4] = 0.0f;

    const float4* src = (const float4*)(in + (size_t)row * DIM);
    float4 a = src[lane];
    float4 b = src[lane + 64];
    float ss = a.x*a.x + a.y*a.y + a.z*a.z + a.w*a.w
             + b.x*b.x + b.y*b.y + b.z*b.z + b.w*b.w;
    #pragma unroll
    for (int m = 1; m < 64; m <<= 1) ss += __shfl_xor(ss, m);
    const float inv = 1.0f / sqrtf(ss);
    ushort4* dst = (ushort4*)(out + (size_t)row * DIM);
    ushort4 o;
    o.x = f2bf(a.x*inv); o.y = f2bf(a.y*inv); o.z = f2bf(a.z*inv); o.w = f2bf(a.w*inv);
    dst[lane] = o;
    o.x = f2bf(b.x*inv); o.y = f2bf(b.y*inv); o.z = f2bf(b.z*inv); o.w = f2bf(b.w*inv);
    dst[lane + 64] = o;
}

// ---------------- Kernel 2: upper-triangle E*E^T, DIRECT global->VGPR fragments ----------
// No LDS, no barriers: E is 8 MB (L2/L3-resident), so MFMA fragments are loaded
// straight from global. Lane l loads E[(r0+(l&15))*512 + ks*32 + (l>>4)*8] as one
// dwordx4 -> 16 rows x 64B = 16 full cache lines per instruction, exactly the
// A/B fragment for mfma_f32_16x16x32_bf16. 2-deep register pipeline, static idx.
// Triangle grid (bi<=bj), 2080 blocks = 8 XCDs x 260 contiguous (bijective).
// 128x128 tile, 4 waves (2x2), per-wave 64x64 output.
__global__ __launch_bounds__(256, 3) void kgemm(const unsigned short* __restrict__ E,
                                                float* __restrict__ pos,
                                                float* __restrict__ neg) {
    const int tid = threadIdx.x;
    const int w = tid >> 6;
    const int l = tid & 63;

    // XCD-contiguous remap (2080 = 8*260), then triangle decode
    int rem = (int)((blockIdx.x & 7) * 260 + (blockIdx.x >> 3));
    int bi = 0;
    while (rem >= 64 - bi) { rem -= 64 - bi; bi++; }
    const int bj = bi + rem;

    const int brow = bi << 7;
    const int bcol = bj << 7;
    const int wr = (w >> 1) << 6;
    const int wc = (w & 1) << 6;

    // per-lane fragment base pointers (bf16x8 units; k advances 32 elems = 4 units)
    const int rA = brow + wr + (l & 15);
    const int rB = bcol + wc + (l & 15);
    const int kb = (l >> 4) << 3;            // 0,8,16,24
    const bf16x8* pA0 = (const bf16x8*)(E + (size_t)rA * DIM + kb);
    const bf16x8* pA1 = (const bf16x8*)(E + (size_t)(rA + 16) * DIM + kb);
    const bf16x8* pA2 = (const bf16x8*)(E + (size_t)(rA + 32) * DIM + kb);
    const bf16x8* pA3 = (const bf16x8*)(E + (size_t)(rA + 48) * DIM + kb);
    const bf16x8* pB0 = (const bf16x8*)(E + (size_t)rB * DIM + kb);
    const bf16x8* pB1 = (const bf16x8*)(E + (size_t)(rB + 16) * DIM + kb);
    const bf16x8* pB2 = (const bf16x8*)(E + (size_t)(rB + 32) * DIM + kb);
    const bf16x8* pB3 = (const bf16x8*)(E + (size_t)(rB + 48) * DIM + kb);

    f32x4 acc[4][4];
    #pragma unroll
    for (int i = 0; i < 4; i++)
        #pragma unroll
        for (int j = 0; j < 4; j++) acc[i][j] = (f32x4)0.0f;

    bf16x8 a0[4], b0[4], a1[4], b1[4];
    a0[0] = pA0[0]; a0[1] = pA1[0]; a0[2] = pA2[0]; a0[3] = pA3[0];
    b0[0] = pB0[0]; b0[1] = pB1[0]; b0[2] = pB2[0]; b0[3] = pB3[0];

    #pragma unroll
    for (int kp = 0; kp < 8; kp++) {
        const int u1 = ((kp << 1) + 1) << 2;     // bf16x8 index of ks=2kp+1
        a1[0] = pA0[u1]; a1[1] = pA1[u1]; a1[2] = pA2[u1]; a1[3] = pA3[u1];
        b1[0] = pB0[u1]; b1[1] = pB1[u1]; b1[2] = pB2[u1]; b1[3] = pB3[u1];
        #pragma unroll
        for (int mi = 0; mi < 4; mi++)
            #pragma unroll
            for (int ni = 0; ni < 4; ni++)
                acc[mi][ni] = __builtin_amdgcn_mfma_f32_16x16x32_bf16(
                    a0[mi], b0[ni], acc[mi][ni], 0, 0, 0);
        if (kp < 7) {
            const int u2 = ((kp << 1) + 2) << 2;
            a0[0] = pA0[u2]; a0[1] = pA1[u2]; a0[2] = pA2[u2]; a0[3] = pA3[u2];
            b0[0] = pB0[u2]; b0[1] = pB1[u2]; b0[2] = pB2[u2]; b0[3] = pB3[u2];
        }
        #pragma unroll
        for (int mi = 0; mi < 4; mi++)
            #pragma unroll
            for (int ni = 0; ni < 4; ni++)
                acc[mi][ni] = __builtin_amdgcn_mfma_f32_16x16x32_bf16(
                    a1[mi], b1[ni], acc[mi][ni], 0, 0, 0);
    }

    // ---- epilogue: exp(10*dot - 10), classify/scatter, reduce, atomics ----
    if (bi == bj) {
        #pragma unroll
        for (int mi = 0; mi < 4; mi++) {
            #pragma unroll
            for (int r = 0; r < 4; r++) {
                const int gi = brow + wr + (mi << 4) + ((l >> 4) << 2) + r;
                float p = 0.0f, n = 0.0f;
                #pragma unroll
                for (int ni = 0; ni < 4; ni++) {
                    const int gj = bcol + wc + (ni << 4) + (l & 15);
                    const float e = __expf(fmaf(acc[mi][ni][r], 10.0f, -10.0f));
                    if (gi == gj) {
                    } else if ((gi >> 2) == (gj >> 2)) {
                        p += e;
                    } else {
                        n += e;
                    }
                }
                #pragma unroll
                for (int m = 1; m < 16; m <<= 1) {
                    n += __shfl_xor(n, m);
                    p += __shfl_xor(p, m);
                }
                if ((l & 15) == 0) {
                    atomicAdd(&neg[gi], n);
                    atomicAdd(&pos[gi], p);
                }
            }
        }
    } else {
        float c[4] = {0.0f, 0.0f, 0.0f, 0.0f};
        #pragma unroll
        for (int mi = 0; mi < 4; mi++) {
            #pragma unroll
            for (int r = 0; r < 4; r++) {
                const int gi = brow + wr + (mi << 4) + ((l >> 4) << 2) + r;
                float n = 0.0f;
                #pragma unroll
                for (int ni = 0; ni < 4; ni++) {
                    const float e = __expf(fmaf(acc[mi][ni][r], 10.0f, -10.0f));
                    n += e;
                    c[ni] += e;
                }
                #pragma unroll
                for (int m = 1; m < 16; m <<= 1) n += __shfl_xor(n, m);
                if ((l & 15) == 0) atomicAdd(&neg[gi], n);
            }
        }
        #pragma unroll
        for (int ni = 0; ni < 4; ni++) {
            c[ni] += __shfl_xor(c[ni], 16);
            c[ni] += __shfl_xor(c[ni], 32);
            if ((l >> 4) == 0) {
                const int gj = bcol + wc + (ni << 4) + (l & 15);
                atomicAdd(&neg[gj], c[ni]);
            }
        }
    }
}

// ---------------- Kernel 3: final loss reduction ----------------
__global__ __launch_bounds__(1024) void kloss(const float* __restrict__ pos,
                                              const float* __restrict__ neg,
                                              float* __restrict__ out) {
    const int tid = threadIdx.x;
    float s = 0.0f;
    for (int i = tid; i < NROWS; i += 1024) {
        const float p = pos[i];
        const float n = neg[i];
        s += logf(p + n + 1e-8f) - logf(p);
    }
    #pragma unroll
    for (int m = 1; m < 64; m <<= 1) s += __shfl_xor(s, m);
    __shared__ float red[16];
    if ((tid & 63) == 0) red[tid >> 6] = s;
    __syncthreads();
    if (tid == 0) {
        float t = 0.0f;
        #pragma unroll
        for (int i = 0; i < 16; i++) t += red[i];
        out[0] = t / (float)NROWS;
    }
}

extern "C" void kernel_launch(void* const* d_in, const int* in_sizes, int n_in,
                              void* d_out, int out_size, void* d_ws, size_t ws_size,
                              hipStream_t stream) {
    (void)in_sizes; (void)n_in; (void)out_size; (void)ws_size;
    const float* emb = (const float*)d_in[0];
    unsigned short* En = (unsigned short*)d_ws;                       // 8 MB bf16
    float* pos = (float*)((char*)d_ws + (size_t)NROWS * DIM * 2);     // 32 KB
    float* neg = pos + NROWS;                                         // 32 KB

    knorm<<<NROWS / 4, 256, 0, stream>>>(emb, En, pos, neg);
    kgemm<<<2080, 256, 0, stream>>>(En, pos, neg);
    kloss<<<1, 1024, 0, stream>>>(pos, neg, (float*)d_out);
}

// Round 5
// 97.425 us; speedup vs baseline: 1.6406x; 1.6406x over previous
//
#include <hip/hip_runtime.h>
#include <hip/hip_bf16.h>
#include <stdint.h>

#define NROWS 8192
#define DIM 512

typedef short bf16x8 __attribute__((ext_vector_type(8)));
typedef float f32x4 __attribute__((ext_vector_type(4)));

__device__ __forceinline__ unsigned short f2bf(float f) {
    union { float f; uint32_t u; } c; c.f = f;
    uint32_t u = c.u;
    return (unsigned short)((u + 0x7FFFu + ((u >> 16) & 1u)) >> 16);
}

__device__ __forceinline__ void gload16(const unsigned short* g, unsigned short* l) {
    __builtin_amdgcn_global_load_lds((const __attribute__((address_space(1))) void*)g,
                                     (__attribute__((address_space(3))) void*)l,
                                     16, 0, 0);
}

// ---------------- Kernel 1: L2-normalize rows -> bf16; also zero pos/neg ----------------
__global__ __launch_bounds__(256) void knorm(const float* __restrict__ in,
                                             unsigned short* __restrict__ out,
                                             float* __restrict__ pos,
                                             float* __restrict__ neg) {
    const int row  = (blockIdx.x << 2) + (threadIdx.x >> 6);
    const int lane = threadIdx.x & 63;
    if (threadIdx.x < 4)      pos[(blockIdx.x << 2) + threadIdx.x] = 0.0f;
    else if (threadIdx.x < 8) neg[(blockIdx.x << 2) + threadIdx.x - 4] = 0.0f;

    const float4* src = (const float4*)(in + (size_t)row * DIM);
    float4 a = src[lane];
    float4 b = src[lane + 64];
    float ss = a.x*a.x + a.y*a.y + a.z*a.z + a.w*a.w
             + b.x*b.x + b.y*b.y + b.z*b.z + b.w*b.w;
    #pragma unroll
    for (int m = 1; m < 64; m <<= 1) ss += __shfl_xor(ss, m);
    const float inv = 1.0f / sqrtf(ss);
    ushort4* dst = (ushort4*)(out + (size_t)row * DIM);
    ushort4 o;
    o.x = f2bf(a.x*inv); o.y = f2bf(a.y*inv); o.z = f2bf(a.z*inv); o.w = f2bf(a.w*inv);
    dst[lane] = o;
    o.x = f2bf(b.x*inv); o.y = f2bf(b.y*inv); o.z = f2bf(b.z*inv); o.w = f2bf(b.w*inv);
    dst[lane + 64] = o;
}

// ---------------- Kernel 2: upper-triangle E*E^T + exp + mask + reduce ----------------
// 128x128 tile, 4 waves (2x2, each 64x64), BK=64, K=512.
// DOUBLE-BUFFERED LDS with COUNTED vmcnt (T3+T4): per K-step
//   barrier (buffer free) -> STAGE next (8 gload_lds/wave) ->
//   s_waitcnt vmcnt(8) (current tile's loads landed; prefetch stays in
//   flight) -> sched_barrier -> barrier -> COMPUTE.
// Raw s_barrier, never drains the prefetch (the R1/R2 __syncthreads drain
// was the 91.5us invariant). Swizzle: linear LDS dest + inverse-swizzled
// global source + same-XOR ds_read (0 conflicts, proven R0-R2).
// Triangle grid (bi<=bj), 2080 blocks = 8 XCDs x 260 contiguous (bijective).
__global__ __launch_bounds__(256) void kgemm(const unsigned short* __restrict__ E,
                                             float* __restrict__ pos,
                                             float* __restrict__ neg) {
    __shared__ unsigned short lds[2][2][8192];   // [buf][A/B][128 rows x 64]

    const int tid = threadIdx.x;
    const int w = tid >> 6;
    const int l = tid & 63;

    // XCD-contiguous remap (2080 = 8*260), then triangle decode
    int rem = (int)((blockIdx.x & 7) * 260 + (blockIdx.x >> 3));
    int bi = 0;
    while (rem >= 64 - bi) { rem -= 64 - bi; bi++; }
    const int bj = bi + rem;

    const int brow = bi << 7;
    const int bcol = bj << 7;
    const int wr = (w >> 1) << 6;
    const int wc = (w & 1) << 6;

    f32x4 acc[4][4];
    #pragma unroll
    for (int i = 0; i < 4; i++)
        #pragma unroll
        for (int j = 0; j < 4; j++) acc[i][j] = (f32x4)0.0f;

    const int g_src = (l & 7) ^ (l >> 3);   // inverse-swizzled source 16B-group

    auto STAGE = [&](int buf, int kt) {
        const size_t colb = (size_t)((kt << 6) + (g_src << 3));
        unsigned short* dA = lds[buf][0];
        unsigned short* dB = lds[buf][1];
        #pragma unroll
        for (int m = 0; m < 4; m++) {
            const int chunk = (w << 2) + m;           // 0..15
            const int r = (chunk << 3) + (l >> 3);    // 0..127 (r&7 == l>>3)
            gload16(E + (size_t)(brow + r) * DIM + colb, &dA[chunk << 9]);
            gload16(E + (size_t)(bcol + r) * DIM + colb, &dB[chunk << 9]);
        }
    };

    auto COMPUTE = [&](int buf) {
        const unsigned short* sA = lds[buf][0];
        const unsigned short* sB = lds[buf][1];
        #pragma unroll
        for (int kk = 0; kk < 2; kk++) {
            bf16x8 aF[4], bF[4];
            const int gk = (kk << 2) + (l >> 4);
            const int gsw = (gk ^ (l & 7)) << 3;
            #pragma unroll
            for (int mi = 0; mi < 4; mi++) {
                const int rr = wr + (mi << 4) + (l & 15);
                aF[mi] = *(const bf16x8*)&sA[(rr << 6) + gsw];
            }
            #pragma unroll
            for (int ni = 0; ni < 4; ni++) {
                const int rr = wc + (ni << 4) + (l & 15);
                bF[ni] = *(const bf16x8*)&sB[(rr << 6) + gsw];
            }
            #pragma unroll
            for (int mi = 0; mi < 4; mi++)
                #pragma unroll
                for (int ni = 0; ni < 4; ni++)
                    acc[mi][ni] = __builtin_amdgcn_mfma_f32_16x16x32_bf16(
                        aF[mi], bF[ni], acc[mi][ni], 0, 0, 0);
        }
    };

    STAGE(0, 0);
    #pragma unroll
    for (int kt = 0; kt < 8; kt++) {
        if (kt > 0) __builtin_amdgcn_s_barrier();    // buffer (kt+1)&1 free
        if (kt < 7) {
            STAGE((kt + 1) & 1, kt + 1);             // prefetch next K-tile
            asm volatile("s_waitcnt vmcnt(8)" ::: "memory");  // cur landed, 8 fly
        } else {
            asm volatile("s_waitcnt vmcnt(0)" ::: "memory");
        }
        __builtin_amdgcn_sched_barrier(0);
        __builtin_amdgcn_s_barrier();                // all waves: cur tile ready
        COMPUTE(kt & 1);
    }

    // ---- epilogue: exp(10*dot - 10), classify/scatter, reduce, atomics ----
    if (bi == bj) {
        #pragma unroll
        for (int mi = 0; mi < 4; mi++) {
            #pragma unroll
            for (int r = 0; r < 4; r++) {
                const int gi = brow + wr + (mi << 4) + ((l >> 4) << 2) + r;
                float p = 0.0f, n = 0.0f;
                #pragma unroll
                for (int ni = 0; ni < 4; ni++) {
                    const int gj = bcol + wc + (ni << 4) + (l & 15);
                    const float e = __expf(fmaf(acc[mi][ni][r], 10.0f, -10.0f));
                    if (gi == gj) {
                    } else if ((gi >> 2) == (gj >> 2)) {
                        p += e;
                    } else {
                        n += e;
                    }
                }
                #pragma unroll
                for (int m = 1; m < 16; m <<= 1) {
                    n += __shfl_xor(n, m);
                    p += __shfl_xor(p, m);
                }
                if ((l & 15) == 0) {
                    atomicAdd(&neg[gi], n);
                    atomicAdd(&pos[gi], p);
                }
            }
        }
    } else {
        float c[4] = {0.0f, 0.0f, 0.0f, 0.0f};
        #pragma unroll
        for (int mi = 0; mi < 4; mi++) {
            #pragma unroll
            for (int r = 0; r < 4; r++) {
                const int gi = brow + wr + (mi << 4) + ((l >> 4) << 2) + r;
                float n = 0.0f;
                #pragma unroll
                for (int ni = 0; ni < 4; ni++) {
                    const float e = __expf(fmaf(acc[mi][ni][r], 10.0f, -10.0f));
                    n += e;
                    c[ni] += e;
                }
                #pragma unroll
                for (int m = 1; m < 16; m <<= 1) n += __shfl_xor(n, m);
                if ((l & 15) == 0) atomicAdd(&neg[gi], n);
            }
        }
        #pragma unroll
        for (int ni = 0; ni < 4; ni++) {
            c[ni] += __shfl_xor(c[ni], 16);
            c[ni] += __shfl_xor(c[ni], 32);
            if ((l >> 4) == 0) {
                const int gj = bcol + wc + (ni << 4) + (l & 15);
                atomicAdd(&neg[gj], c[ni]);
            }
        }
    }
}

// ---------------- Kernel 3: final loss reduction ----------------
__global__ __launch_bounds__(1024) void kloss(const float* __restrict__ pos,
                                              const float* __restrict__ neg,
                                              float* __restrict__ out) {
    const int tid = threadIdx.x;
    float s = 0.0f;
    for (int i = tid; i < NROWS; i += 1024) {
        const float p = pos[i];
        const float n = neg[i];
        s += logf(p + n + 1e-8f) - logf(p);
    }
    #pragma unroll
    for (int m = 1; m < 64; m <<= 1) s += __shfl_xor(s, m);
    __shared__ float red[16];
    if ((tid & 63) == 0) red[tid >> 6] = s;
    __syncthreads();
    if (tid == 0) {
        float t = 0.0f;
        #pragma unroll
        for (int i = 0; i < 16; i++) t += red[i];
        out[0] = t / (float)NROWS;
    }
}

extern "C" void kernel_launch(void* const* d_in, const int* in_sizes, int n_in,
                              void* d_out, int out_size, void* d_ws, size_t ws_size,
                              hipStream_t stream) {
    (void)in_sizes; (void)n_in; (void)out_size; (void)ws_size;
    const float* emb = (const float*)d_in[0];
    unsigned short* En = (unsigned short*)d_ws;                       // 8 MB bf16
    float* pos = (float*)((char*)d_ws + (size_t)NROWS * DIM * 2);     // 32 KB
    float* neg = pos + NROWS;                                         // 32 KB

    knorm<<<NROWS / 4, 256, 0, stream>>>(emb, En, pos, neg);
    kgemm<<<2080, 256, 0, stream>>>(En, pos, neg);
    kloss<<<1, 1024, 0, stream>>>(pos, neg, (float*)d_out);
}

// Round 6
// 89.637 us; speedup vs baseline: 1.7831x; 1.0869x over previous
//
#include <hip/hip_runtime.h>
#include <hip/hip_bf16.h>
#include <stdint.h>

#define NROWS 8192
#define DIM 512

typedef short bf16x8 __attribute__((ext_vector_type(8)));
typedef float f32x4 __attribute__((ext_vector_type(4)));

__device__ __forceinline__ unsigned short f2bf(float f) {
    union { float f; uint32_t u; } c; c.f = f;
    uint32_t u = c.u;
    return (unsigned short)((u + 0x7FFFu + ((u >> 16) & 1u)) >> 16);
}

__device__ __forceinline__ void gload16(const unsigned short* g, unsigned short* l) {
    __builtin_amdgcn_global_load_lds((const __attribute__((address_space(1))) void*)g,
                                     (__attribute__((address_space(3))) void*)l,
                                     16, 0, 0);
}

// ---------------- Kernel 1: L2-normalize rows -> bf16; also zero pos/neg ----------------
__global__ __launch_bounds__(256) void knorm(const float* __restrict__ in,
                                             unsigned short* __restrict__ out,
                                             float* __restrict__ pos,
                                             float* __restrict__ neg) {
    const int row  = (blockIdx.x << 2) + (threadIdx.x >> 6);
    const int lane = threadIdx.x & 63;
    if (threadIdx.x < 4)      pos[(blockIdx.x << 2) + threadIdx.x] = 0.0f;
    else if (threadIdx.x < 8) neg[(blockIdx.x << 2) + threadIdx.x - 4] = 0.0f;

    const float4* src = (const float4*)(in + (size_t)row * DIM);
    float4 a = src[lane];
    float4 b = src[lane + 64];
    float ss = a.x*a.x + a.y*a.y + a.z*a.z + a.w*a.w
             + b.x*b.x + b.y*b.y + b.z*b.z + b.w*b.w;
    #pragma unroll
    for (int m = 1; m < 64; m <<= 1) ss += __shfl_xor(ss, m);
    const float inv = 1.0f / sqrtf(ss);
    ushort4* dst = (ushort4*)(out + (size_t)row * DIM);
    ushort4 o;
    o.x = f2bf(a.x*inv); o.y = f2bf(a.y*inv); o.z = f2bf(a.z*inv); o.w = f2bf(a.w*inv);
    dst[lane] = o;
    o.x = f2bf(b.x*inv); o.y = f2bf(b.y*inv); o.z = f2bf(b.z*inv); o.w = f2bf(b.w*inv);
    dst[lane + 64] = o;
}

// ---------------- Kernel 2: upper-triangle E*E^T + exp + mask + reduce ----------------
// 256x256 tile, 16 waves (4x4, each 64x64), BK=32, K=512 -> 16 K-steps.
// LDS 64 KB: lds[2][2][256*32] double-buffered, counted-vmcnt schedule
// (STAGE next -> vmcnt(2) -> sched_barrier -> s_barrier -> COMPUTE; never
// drains prefetch). Supertile XCD map (R2-verified, FETCH 28 MB): triangle
// of 4x4 supertiles of 8x8 blocks; 528 = 8 XCDs x 66 contiguous.
// Swizzle (rows are 64 B = 4 16B-groups): stored group = g ^ ((r>>1)&3);
// linear LDS dest + inverse-swizzled global source + same-XOR ds_read ->
// 2 lanes/bank on b128 reads (free per m136).
__global__ __launch_bounds__(1024, 1) void kgemm(const unsigned short* __restrict__ E,
                                                 float* __restrict__ pos,
                                                 float* __restrict__ neg) {
    __shared__ unsigned short lds[2][2][256 * 32];   // [buf][A/B][256 rows x 32]

    const int tid = threadIdx.x;
    const int w = tid >> 6;          // 0..15
    const int l = tid & 63;

    // ---- block id -> (bi, bj): supertile triangle decode (R2-verified) ----
    int rem = (int)((blockIdx.x & 7) * 66 + (blockIdx.x >> 3));
    int SI = -1, SJ = -1;
    #pragma unroll
    for (int s = 0; s < 10; s++) {
        constexpr int si_t[10] = {0,0,0,0,1,1,1,2,2,3};
        constexpr int sj_t[10] = {0,1,2,3,1,2,3,2,3,3};
        const int sz = (si_t[s] == sj_t[s]) ? 36 : 64;
        if (SI < 0) {
            if (rem < sz) { SI = si_t[s]; SJ = sj_t[s]; }
            else rem -= sz;
        }
    }
    int bi, bj;
    if (SI == SJ) {
        int x = 0;
        while (rem >= 8 - x) { rem -= 8 - x; x++; }
        bi = (SI << 3) + x; bj = (SI << 3) + x + rem;
    } else {
        bi = (SI << 3) + (rem >> 3);
        bj = (SJ << 3) + (rem & 7);
    }

    const int brow = bi << 8;
    const int bcol = bj << 8;
    const int wr = (w >> 2) << 6;        // 0,64,128,192
    const int wc = (w & 3) << 6;         // 0,64,128,192

    f32x4 acc[4][4];
    #pragma unroll
    for (int i = 0; i < 4; i++)
        #pragma unroll
        for (int j = 0; j < 4; j++) acc[i][j] = (f32x4)0.0f;

    // staging: each wave stages chunk w (16 rows) of A and B. lane l ->
    // row_local = l>>2, stored slot = l&3; source group inverse-swizzled.
    const int g_src = (l & 3) ^ ((l >> 3) & 3);
    const int r_st  = (w << 4) + (l >> 2);          // tile row 0..255

    auto STAGE = [&](int buf, int kt) {
        const size_t colb = (size_t)((kt << 5) + (g_src << 3));
        gload16(E + (size_t)(brow + r_st) * DIM + colb, &lds[buf][0][w << 9]);
        gload16(E + (size_t)(bcol + r_st) * DIM + colb, &lds[buf][1][w << 9]);
    };

    const int sgk = (((l >> 4) ^ ((l >> 1) & 3)) << 3);  // swizzled ushort offset

    auto COMPUTE = [&](int buf) {
        const unsigned short* sA = lds[buf][0];
        const unsigned short* sB = lds[buf][1];
        bf16x8 aF[4], bF[4];
        #pragma unroll
        for (int mi = 0; mi < 4; mi++) {
            const int rr = wr + (mi << 4) + (l & 15);
            aF[mi] = *(const bf16x8*)&sA[(rr << 5) + sgk];
        }
        #pragma unroll
        for (int ni = 0; ni < 4; ni++) {
            const int rr = wc + (ni << 4) + (l & 15);
            bF[ni] = *(const bf16x8*)&sB[(rr << 5) + sgk];
        }
        #pragma unroll
        for (int mi = 0; mi < 4; mi++)
            #pragma unroll
            for (int ni = 0; ni < 4; ni++)
                acc[mi][ni] = __builtin_amdgcn_mfma_f32_16x16x32_bf16(
                    aF[mi], bF[ni], acc[mi][ni], 0, 0, 0);
    };

    STAGE(0, 0);
    #pragma unroll
    for (int kt = 0; kt < 16; kt++) {
        if (kt > 0) __builtin_amdgcn_s_barrier();        // prev buffer free
        if (kt < 15) {
            STAGE((kt + 1) & 1, kt + 1);                 // prefetch next
            asm volatile("s_waitcnt vmcnt(2)" ::: "memory");  // cur landed
        } else {
            asm volatile("s_waitcnt vmcnt(0)" ::: "memory");
        }
        __builtin_amdgcn_sched_barrier(0);
        __builtin_amdgcn_s_barrier();                    // cur tile ready
        COMPUTE(kt & 1);
    }

    // ---- epilogue: exp(10*dot - 10), classify/scatter, reduce, atomics ----
    if (bi == bj) {
        #pragma unroll
        for (int mi = 0; mi < 4; mi++) {
            #pragma unroll
            for (int r = 0; r < 4; r++) {
                const int gi = brow + wr + (mi << 4) + ((l >> 4) << 2) + r;
                float p = 0.0f, n = 0.0f;
                #pragma unroll
                for (int ni = 0; ni < 4; ni++) {
                    const int gj = bcol + wc + (ni << 4) + (l & 15);
                    const float e = __expf(fmaf(acc[mi][ni][r], 10.0f, -10.0f));
                    if (gi == gj) {
                    } else if ((gi >> 2) == (gj >> 2)) {
                        p += e;
                    } else {
                        n += e;
                    }
                }
                #pragma unroll
                for (int m = 1; m < 16; m <<= 1) {
                    n += __shfl_xor(n, m);
                    p += __shfl_xor(p, m);
                }
                if ((l & 15) == 0) {
                    atomicAdd(&neg[gi], n);
                    atomicAdd(&pos[gi], p);
                }
            }
        }
    } else {
        float c[4] = {0.0f, 0.0f, 0.0f, 0.0f};
        #pragma unroll
        for (int mi = 0; mi < 4; mi++) {
            #pragma unroll
            for (int r = 0; r < 4; r++) {
                const int gi = brow + wr + (mi << 4) + ((l >> 4) << 2) + r;
                float n = 0.0f;
                #pragma unroll
                for (int ni = 0; ni < 4; ni++) {
                    const float e = __expf(fmaf(acc[mi][ni][r], 10.0f, -10.0f));
                    n += e;
                    c[ni] += e;
                }
                #pragma unroll
                for (int m = 1; m < 16; m <<= 1) n += __shfl_xor(n, m);
                if ((l & 15) == 0) atomicAdd(&neg[gi], n);
            }
        }
        #pragma unroll
        for (int ni = 0; ni < 4; ni++) {
            c[ni] += __shfl_xor(c[ni], 16);
            c[ni] += __shfl_xor(c[ni], 32);
            if ((l >> 4) == 0) {
                const int gj = bcol + wc + (ni << 4) + (l & 15);
                atomicAdd(&neg[gj], c[ni]);
            }
        }
    }
}

// ---------------- Kernel 3: final loss reduction ----------------
__global__ __launch_bounds__(1024) void kloss(const float* __restrict__ pos,
                                              const float* __restrict__ neg,
                                              float* __restrict__ out) {
    const int tid = threadIdx.x;
    float s = 0.0f;
    for (int i = tid; i < NROWS; i += 1024) {
        const float p = pos[i];
        const float n = neg[i];
        s += logf(p + n + 1e-8f) - logf(p);
    }
    #pragma unroll
    for (int m = 1; m < 64; m <<= 1) s += __shfl_xor(s, m);
    __shared__ float red[16];
    if ((tid & 63) == 0) red[tid >> 6] = s;
    __syncthreads();
    if (tid == 0) {
        float t = 0.0f;
        #pragma unroll
        for (int i = 0; i < 16; i++) t += red[i];
        out[0] = t / (float)NROWS;
    }
}

extern "C" void kernel_launch(void* const* d_in, const int* in_sizes, int n_in,
                              void* d_out, int out_size, void* d_ws, size_t ws_size,
                              hipStream_t stream) {
    (void)in_sizes; (void)n_in; (void)out_size; (void)ws_size;
    const float* emb = (const float*)d_in[0];
    unsigned short* En = (unsigned short*)d_ws;                       // 8 MB bf16
    float* pos = (float*)((char*)d_ws + (size_t)NROWS * DIM * 2);     // 32 KB
    float* neg = pos + NROWS;                                         // 32 KB

    knorm<<<NROWS / 4, 256, 0, stream>>>(emb, En, pos, neg);
    kgemm<<<528, 1024, 0, stream>>>(En, pos, neg);
    kloss<<<1, 1024, 0, stream>>>(pos, neg, (float*)d_out);
}